// Round 1
// baseline (619.889 us; speedup 1.0000x reference)
//
#include <hip/hip_runtime.h>

// LocSE: B=4, N=16384, DIMS=2, K1=17, CH=53, UNITS=128 (UH=64)
// Inputs: pc(4,16384,2) f32, feats(4,16384,64) f32, n_idx(4,16384,17) i32,
//         W(53,64) f32, b(64) f32
// Outputs (concat flat): out(4,16384,17,128) f32 then ggf(4,16384,1,2) f32
//
// Algebra: for row j, rppe channels are [p_j | {p_i-p_j, norm_j}_i], so
//   r[j][u] = relu(b[u] + G[u] + p_jx*(W0-SWx) + p_jy*(W1-SWy) + nr_j*SWn)
// with G[u] = sum_i (p_ix*W[2+3i][u] + p_iy*W[3+3i][u])  (j-independent),
//      SWx/SWy/SWn = column sums of the per-i W rows.
// NOTE: nb in the reference broadcasts norms[j] across i (axis-3), hence the
// single nr_j*SWn term.

#define NB 16384
#define K1C 17
#define UH 64

static constexpr long long OUT_R = 4LL * NB * K1C * 128; // 142606336

__global__ __launch_bounds__(256) void locse_kernel(
    const float* __restrict__ pc,
    const float* __restrict__ feats,
    const int*   __restrict__ n_idx,
    const float* __restrict__ W,
    const float* __restrict__ bias,
    float* __restrict__ out)
{
    __shared__ float s_px[4][K1C];
    __shared__ float s_py[4][K1C];
    __shared__ float s_nr[4][K1C];
    __shared__ int   s_id[4][K1C];

    const int wave = threadIdx.x >> 6;
    const int lane = threadIdx.x & 63;
    const long long p = (long long)blockIdx.x * 4 + wave;   // point in [0, 65536)
    const int bidx = (int)(p >> 14);                        // p / N

    // Phase A: gather the 17 neighbour points, stage in LDS
    if (lane < K1C) {
        int id = n_idx[p * K1C + lane];
        s_id[wave][lane] = id;
        const float* pp = pc + ((long long)bidx * NB + id) * 2;
        float x = pp[0];
        float y = pp[1];
        s_px[wave][lane] = x;
        s_py[wave][lane] = y;
        s_nr[wave][lane] = sqrtf(fmaf(x, x, y * y));
    }
    __syncthreads();

    // Phase B: per-lane unit u = lane
    const int u = lane;
    float w0 = W[u];        // W[0][u]
    float w1 = W[UH + u];   // W[1][u]
    const float* Wr = W + 2 * UH + u;

    float G = 0.f, swx = 0.f, swy = 0.f, swn = 0.f;
    float sx = 0.f, sy = 0.f, sxx = 0.f, syy = 0.f, sxy = 0.f;
#pragma unroll
    for (int i = 0; i < K1C; ++i) {
        float px = s_px[wave][i];   // LDS broadcast (same addr all lanes)
        float py = s_py[wave][i];
        float wx = Wr[(3 * i + 0) * UH];  // coalesced, W is L1/L2 resident
        float wy = Wr[(3 * i + 1) * UH];
        float wn = Wr[(3 * i + 2) * UH];
        G = fmaf(px, wx, G);
        G = fmaf(py, wy, G);
        swx += wx; swy += wy; swn += wn;
        sx += px;  sy += py;
        sxx = fmaf(px, px, sxx);
        syy = fmaf(py, py, syy);
        sxy = fmaf(px, py, sxy);
    }
    float base = bias[u] + G;
    float c0 = w0 - swx;
    float c1 = w1 - swy;

    const long long fb = (long long)bidx * NB * UH;
    float* orow = out + p * (K1C * 128);
#pragma unroll
    for (int j = 0; j < K1C; ++j) {
        float v = fmaf(s_px[wave][j], c0,
                  fmaf(s_py[wave][j], c1,
                  fmaf(s_nr[wave][j], swn, base)));
        v = fmaxf(v, 0.f);
        float f = feats[fb + (long long)s_id[wave][j] * UH + u];
        orow[j * 128 + u]      = f;  // n_feats half
        orow[j * 128 + UH + u] = v;  // relu-MLP half
    }

    // ggf: slope + (1 - pearson) over the 17 neighbour coords
    if (lane == 0) {
        const float inv = 1.0f / 17.0f;
        float mx = sx * inv, my = sy * inv;
        float cov = sxy * inv - mx * my;
        float vx = fmaxf(sxx * inv - mx * mx, 0.f);
        float vy = fmaxf(syy * inv - my * my, 0.f);
        float m = cov / (vx + 1e-8f);
        float pear = cov / (sqrtf(vx * vy) + 1e-8f);
        out[OUT_R + p * 2 + 0] = m;
        out[OUT_R + p * 2 + 1] = 1.0f - pear;
    }
}

extern "C" void kernel_launch(void* const* d_in, const int* in_sizes, int n_in,
                              void* d_out, int out_size, void* d_ws, size_t ws_size,
                              hipStream_t stream) {
    const float* pc    = (const float*)d_in[0];
    const float* feats = (const float*)d_in[1];
    const int*   n_idx = (const int*)d_in[2];
    const float* W     = (const float*)d_in[3];
    const float* bias  = (const float*)d_in[4];
    float* out = (float*)d_out;

    // 65536 points, 4 per block (one wave each), 256 threads
    locse_kernel<<<16384, 256, 0, stream>>>(pc, feats, n_idx, W, bias, out);
}